// Round 5
// baseline (771.266 us; speedup 1.0000x reference)
//
#include <hip/hip_runtime.h>
#include <hip/hip_bf16.h>

// Problem constants
#define B_    1024
#define DIMC  64      // DIM
#define T_    255     // S-1 sequence steps
#define H_    128
#define CS_   500
#define S_    256

#define MROWS 32             // batch rows per block = 2 groups of 16
#define NBLK  (B_ / MROWS)   // 32 blocks
#define NTHR  512            // 8 waves; each wave owns 16 gate-cols for BOTH groups
#define TCH   2              // timesteps staged per chunk
#define XSTR  136            // padded LDS row stride (bf16 elems)

// LDS carve (bytes):
//   shx: 2 bufs x TCH x 32 rows x 136 x 2B = 34,816   @ 0
//   shh: 2 bufs x 2 grp x 16 x 136 x 2B    = 17,408   @ 34,816
//   epilogue scratch reuses bytes 0..86,208 (x/h dead there)
//   sidx: 32*64*4 = 8,192                              @ 87,040 (survives epilogue)
#define OFF_H   34816
#define OFF_IDX 87040
#define SMEMB   95232

typedef __attribute__((ext_vector_type(8))) short bf16x8;
typedef __attribute__((ext_vector_type(4))) float f32x4;
typedef __attribute__((ext_vector_type(2))) float f32x2;

__device__ __forceinline__ unsigned short f2bf(float f) {
    unsigned int u = __builtin_bit_cast(unsigned int, f);
    return (unsigned short)((u + 0x7FFFu + ((u >> 16) & 1u)) >> 16);
}
__device__ __forceinline__ float fast_rcp(float x) { return __builtin_amdgcn_rcpf(x); }
__device__ __forceinline__ float sigm(float x)   { float e = __expf(-x); return fast_rcp(1.0f + e); }
__device__ __forceinline__ float tanh_f(float x) { float e = __expf(2.0f * x); return 1.0f - 2.0f * fast_rcp(1.0f + e); }
__device__ __forceinline__ float leaky(float x)  { return x > 0.0f ? x : 0.01f * x; }
// Barrier WITHOUT vmcnt drain: keeps prefetch global loads in flight.
__device__ __forceinline__ void bar_lgkm() {
    asm volatile("s_waitcnt lgkmcnt(0)\n\ts_barrier" ::: "memory");
}

// Epilogue LDS layout (dword offsets; all < 87,040/4)
#define OW1 0        // W1 padded 64 x 129
#define OW2 8256     // W2 padded 32 x 65
#define OW3 10336    // W3 padded 16 x 33
#define OWL 10864    // W_last padded 64 x 81
#define OHF 16048    // h fp32, 32 x 128
#define OS1 20144    // s1 per wave 8 x 64
#define OS2 20656    // s2 per wave 8 x 32
#define OS3 20912    // s3 per wave 8 x 16
#define OSL 21040    // last per wave 8 x 64  (ends 21,552 dw = 86,208 B)

__global__ __launch_bounds__(NTHR, 2)
void gru_fused(const float* __restrict__ x, const int* __restrict__ snippet,
               const float* __restrict__ slist,
               const float* __restrict__ W_ih, const float* __restrict__ W_hh,
               const float* __restrict__ b_ih, const float* __restrict__ b_hh,
               const float* __restrict__ W1, const float* __restrict__ b1,
               const float* __restrict__ W2, const float* __restrict__ b2,
               const float* __restrict__ W3, const float* __restrict__ b3,
               const float* __restrict__ Wl, const float* __restrict__ bl,
               float* __restrict__ out)
{
    __shared__ __attribute__((aligned(16))) unsigned char smem[SMEMB];
    unsigned short* shx = (unsigned short*)smem;             // [2][TCH][32][XSTR]
    unsigned short* shh = (unsigned short*)(smem + OFF_H);   // [2][2][16][XSTR]
    int*            sidx = (int*)(smem + OFF_IDX);           // [32*64]

    const int tid   = threadIdx.x;
    const int bbase = blockIdx.x * MROWS;
    const int lane  = tid & 63;
    const int wv    = tid >> 6;          // 0..7
    const int l15   = lane & 15;
    const int l4    = lane >> 4;

    // ---- snippet indices, zero h buffer 0 (both groups) ----
    for (int i = tid; i < MROWS * DIMC; i += NTHR) {
        int r = i >> 6, d = i & 63;
        sidx[i] = snippet[(bbase + r) * DIMC + d];
    }
    for (int i = tid; i < 2 * 16 * XSTR; i += NTHR) shh[i] = 0;

    // ---- weight B-fragments in registers (whole kernel): 96 VGPR ----
    bf16x8 wih[3][4], whh[3][4];
    {
        const int g = (wv << 4) + l15;
#pragma unroll
        for (int gt = 0; gt < 3; ++gt) {
#pragma unroll
            for (int kb = 0; kb < 4; ++kb) {
                const float* p1 = W_ih + (size_t)(gt * 128 + g) * 128 + kb * 32 + (l4 << 3);
                const float* p2 = W_hh + (size_t)(gt * 128 + g) * 128 + kb * 32 + (l4 << 3);
                f32x4 a0, a1, c0, c1;
                __builtin_memcpy(&a0, p1, 16); __builtin_memcpy(&a1, p1 + 4, 16);
                __builtin_memcpy(&c0, p2, 16); __builtin_memcpy(&c1, p2 + 4, 16);
                bf16x8 a, c;
#pragma unroll
                for (int e = 0; e < 4; ++e) {
                    a[e] = (short)f2bf(a0[e]); a[e + 4] = (short)f2bf(a1[e]);
                    c[e] = (short)f2bf(c0[e]); c[e + 4] = (short)f2bf(c1[e]);
                }
                wih[gt][kb] = a; whh[gt][kb] = c;
            }
        }
    }
    const int jj = (wv << 4) + l15;
    const float bias_r = b_ih[jj]       + b_hh[jj];
    const float bias_z = b_ih[128 + jj] + b_hh[128 + jj];
    const float bxn    = b_ih[256 + jj];
    const float bhn    = b_hh[256 + jj];

    __syncthreads();   // sidx ready, h0 zeroed

    // ---- staging: 4 units/thread; unit un = (row = tid/64 + 8*un, even k0) ----
    const int k0  = (tid & 63) << 1;
    const int isx = (k0 < DIMC);
    const float* pa[4]; const float* pb[4];
    int rowu[4];
#pragma unroll
    for (int un = 0; un < 4; ++un) {
        int r = (tid >> 6) + (un << 3);
        rowu[un] = r;
        if (isx) {
            pa[un] = x + ((size_t)(bbase + r) * DIMC + k0) * T_;
            pb[un] = pa[un] + T_;
        } else {
            int d = k0 - DIMC;
            pa[un] = slist + ((size_t)d       * CS_ + sidx[(r << 6) + d])     * S_;
            pb[un] = slist + ((size_t)(d + 1) * CS_ + sidx[(r << 6) + d + 1]) * S_;
        }
    }

    f32x2 sa[4], sb[4];   // TCH=2 timesteps x 2 k per unit: 16 VGPR

    auto issue = [&](int t0) {
        if (isx && t0 >= T_ - 1) {          // x tail clamp (t0 = 254)
#pragma unroll
            for (int un = 0; un < 4; ++un) {
                float va = pa[un][T_ - 1], vb = pb[un][T_ - 1];
                sa[un] = f32x2{va, va}; sb[un] = f32x2{vb, vb};
            }
        } else {
#pragma unroll
            for (int un = 0; un < 4; ++un) {
                f32x2 va, vb;
                __builtin_memcpy(&va, pa[un] + t0, 8);
                __builtin_memcpy(&vb, pb[un] + t0, 8);
                sa[un] = va; sb[un] = vb;
            }
        }
    };

    auto commit = [&](int buf) {
        unsigned short* dst = shx + buf * (TCH * MROWS * XSTR);
#pragma unroll
        for (int un = 0; un < 4; ++un) {
#pragma unroll
            for (int e = 0; e < TCH; ++e) {
                unsigned pk = (unsigned)f2bf(sa[un][e]) | ((unsigned)f2bf(sb[un][e]) << 16);
                *(unsigned*)&dst[(e * MROWS + rowu[un]) * XSTR + k0] = pk;
            }
        }
    };

    int cur = 0;
    float hprevA[4] = {0.f, 0.f, 0.f, 0.f};
    float hprevB[4] = {0.f, 0.f, 0.f, 0.f};

    // one group's full step: JIT xg (4-deep x-chains) + h-chains (4-deep) + gates + write
    auto recone = [&](int bx, int st, int grp, float* hprev) {
        const unsigned short* xp = shx + ((bx * TCH + st) * MROWS + (grp << 4) + l15) * XSTR + (l4 << 3);
        const unsigned short* hp = shh + ((cur * 2 + grp) * 16 + l15) * XSTR + (l4 << 3);
        bf16x8 xf[4], hf[4];
#pragma unroll
        for (int kb = 0; kb < 4; ++kb) {
            xf[kb] = *(const bf16x8*)(xp + kb * 32);
            hf[kb] = *(const bf16x8*)(hp + kb * 32);
        }
        f32x4 aXr = {bias_r, bias_r, bias_r, bias_r};
        f32x4 aXz = {bias_z, bias_z, bias_z, bias_z};
        f32x4 aXn = {bxn, bxn, bxn, bxn};
        f32x4 aHr = {0.f, 0.f, 0.f, 0.f};
        f32x4 aHz = {0.f, 0.f, 0.f, 0.f};
        f32x4 aHn = {bhn, bhn, bhn, bhn};
#pragma unroll
        for (int kb = 0; kb < 4; ++kb) {
            aXr = __builtin_amdgcn_mfma_f32_16x16x32_bf16(xf[kb], wih[0][kb], aXr, 0, 0, 0);
            aHr = __builtin_amdgcn_mfma_f32_16x16x32_bf16(hf[kb], whh[0][kb], aHr, 0, 0, 0);
            aXz = __builtin_amdgcn_mfma_f32_16x16x32_bf16(xf[kb], wih[1][kb], aXz, 0, 0, 0);
            aHz = __builtin_amdgcn_mfma_f32_16x16x32_bf16(hf[kb], whh[1][kb], aHz, 0, 0, 0);
            aXn = __builtin_amdgcn_mfma_f32_16x16x32_bf16(xf[kb], wih[2][kb], aXn, 0, 0, 0);
            aHn = __builtin_amdgcn_mfma_f32_16x16x32_bf16(hf[kb], whh[2][kb], aHn, 0, 0, 0);
        }
        unsigned short* hw = shh + ((cur ^ 1) * 2 + grp) * (16 * XSTR);
#pragma unroll
        for (int q = 0; q < 4; ++q) {
            float r  = sigm(aXr[q] + aHr[q]);
            float z  = sigm(aXz[q] + aHz[q]);
            float n  = tanh_f(aXn[q] + r * aHn[q]);
            float hn = n + z * (hprev[q] - n);
            hprev[q] = hn;
            hw[((l4 << 2) + q) * XSTR + jj] = f2bf(hn);
        }
    };

    // ---- prologue: stage chunk 0 ----
    issue(0);
    commit(0);
    __syncthreads();

    // ---- main: 127 chunks of 2 steps (t = 0..253) ----
    for (int c = 0; c < 127; ++c) {
        issue((c + 1) * TCH);               // prefetch; raw barriers keep loads in flight
        const int bx = c & 1;
        recone(bx, 0, 0, hprevA);
        recone(bx, 0, 1, hprevB);
        bar_lgkm(); cur ^= 1;
        commit((c + 1) & 1);                // buffer bx^1 free this chunk
        recone(bx, 1, 0, hprevA);
        recone(bx, 1, 1, hprevB);
        bar_lgkm(); cur ^= 1;
    }
    // ---- tail: t = 254, chunk 127 (buf 1, st 0) ----
    recone(1, 0, 0, hprevA);
    recone(1, 0, 1, hprevB);
    __syncthreads();

    // ================= fused MLP epilogue (LDS-resident weights) =================
    float* wl = (float*)smem;   // x/h regions dead; sidx (>=87,040 B) preserved

    for (int i = tid; i < 8192; i += NTHR) wl[OW1 + (i >> 7) * 129 + (i & 127)] = W1[i];
    for (int i = tid; i < 2048; i += NTHR) wl[OW2 + (i >> 6) * 65  + (i & 63)]  = W2[i];
    for (int i = tid; i < 512;  i += NTHR) wl[OW3 + (i >> 5) * 33  + (i & 31)]  = W3[i];
    for (int i = tid; i < 5120; i += NTHR) wl[OWL + (i / 80) * 81  + (i % 80)]  = Wl[i];
#pragma unroll
    for (int q = 0; q < 4; ++q) {
        wl[OHF + (((l4 << 2) + q)) * 128 + jj]      = hprevA[q];
        wl[OHF + (16 + ((l4 << 2) + q)) * 128 + jj] = hprevB[q];
    }
    __syncthreads();

    // wave wv handles batch rows wv*4 .. wv*4+3
    for (int mloc = 0; mloc < 4; ++mloc) {
        const int m = (wv << 2) + mloc;
        {
            float s = b1[lane];
            const float* w = wl + OW1 + lane * 129;
            for (int k = 0; k < 128; ++k) s += wl[OHF + m * 128 + k] * w[k];
            wl[OS1 + wv * 64 + lane] = leaky(s);
        }
        __syncthreads();
        if (lane < 32) {
            float s = b2[lane];
            const float* w = wl + OW2 + lane * 65;
            for (int k = 0; k < 64; ++k) s += wl[OS1 + wv * 64 + k] * w[k];
            wl[OS2 + wv * 32 + lane] = leaky(s);
        } else {
            int d = lane - 32;
            wl[OSL + wv * 64 + d]      = slist[((size_t)d        * CS_ + sidx[(m << 6) + d])      * S_ + (S_ - 1)];
            wl[OSL + wv * 64 + d + 32] = slist[((size_t)(d + 32) * CS_ + sidx[(m << 6) + d + 32]) * S_ + (S_ - 1)];
        }
        __syncthreads();
        if (lane < 16) {
            float s = b3[lane];
            const float* w = wl + OW3 + lane * 33;
            for (int k = 0; k < 32; ++k) s += wl[OS2 + wv * 32 + k] * w[k];
            wl[OS3 + wv * 16 + lane] = leaky(s);
        }
        __syncthreads();
        {
            float s = bl[lane];
            const float* w = wl + OWL + lane * 81;
#pragma unroll
            for (int i = 0; i < 16; ++i) s += wl[OS3 + wv * 16 + i] * w[i];
            for (int d = 0; d < 64; ++d) s += wl[OSL + wv * 64 + d] * w[16 + d];
            out[(size_t)(bbase + m) * DIMC + lane] = leaky(s);
        }
        __syncthreads();
    }
}

extern "C" void kernel_launch(void* const* d_in, const int* in_sizes, int n_in,
                              void* d_out, int out_size, void* d_ws, size_t ws_size,
                              hipStream_t stream) {
    (void)in_sizes; (void)n_in; (void)out_size; (void)d_ws; (void)ws_size;
    const float* x       = (const float*)d_in[0];
    const int*   snippet = (const int*)  d_in[1];
    const float* slist   = (const float*)d_in[2];
    const float* W_ih    = (const float*)d_in[3];
    const float* W_hh    = (const float*)d_in[4];
    const float* b_ih    = (const float*)d_in[5];
    const float* b_hh    = (const float*)d_in[6];
    const float* W1      = (const float*)d_in[7];
    const float* b1      = (const float*)d_in[8];
    const float* W2      = (const float*)d_in[9];
    const float* b2      = (const float*)d_in[10];
    const float* W3      = (const float*)d_in[11];
    const float* b3      = (const float*)d_in[12];
    const float* Wl      = (const float*)d_in[13];
    const float* bl      = (const float*)d_in[14];
    float* out = (float*)d_out;

    hipLaunchKernelGGL(gru_fused, dim3(NBLK), dim3(NTHR), 0, stream,
                       x, snippet, slist, W_ih, W_hh, b_ih, b_hh,
                       W1, b1, W2, b2, W3, b3, Wl, bl, out);
}